// Round 4
// baseline (234.764 us; speedup 1.0000x reference)
//
#include <hip/hip_runtime.h>
#include <math.h>

// (B,T,D) = (32, 2048, 512), fp32 in, fp32 out.
constexpr int B = 32;
constexpr int T = 2048;
constexpr int D = 512;

constexpr int C1 = 32;            // K1: chunks over T (1024 blocks, 4/CU)
constexpr int R1 = T / C1;        // 64 rows per K1 block
constexpr int C2 = 32;            // K2: blocks per batch
constexpr int R2 = T / C2;        // 64 rows per K2 block (16 per wave)
constexpr int NPART = C2 * 4;     // 128 wave-partials per batch

// ---------------- K1: partial column sums, no atomics ----------------
// P1[b][c][d] = sum_{t in chunk c} x[b][t][d]
__global__ __launch_bounds__(256) void colsum_part(const float* __restrict__ x,
                                                   float* __restrict__ P1) {
    const int b = blockIdx.x, c = blockIdx.y;
    const int d4 = threadIdx.x & 127;      // float4 column
    const int rp = threadIdx.x >> 7;       // row parity
    const float4* xp = (const float4*)x + ((size_t)(b * T + c * R1) * D >> 2)
                       + (size_t)rp * (D / 4) + d4;
    float4 acc = {0.f, 0.f, 0.f, 0.f};
    #pragma unroll 8
    for (int i = 0; i < R1 / 2; ++i) {
        float4 v = xp[(size_t)i * (D / 2)];
        acc.x += v.x; acc.y += v.y; acc.z += v.z; acc.w += v.w;
    }
    __shared__ float4 lds[128];
    if (rp == 1) lds[d4] = acc;
    __syncthreads();
    if (rp == 0) {
        float4 o = lds[d4];
        acc.x += o.x; acc.y += o.y; acc.z += o.z; acc.w += o.w;
        ((float4*)P1)[(size_t)(b * C1 + c) * (D / 4) + d4] = acc;
    }
}

// ---------------- K2: fused rowdot + online softmax + pool (fp32) ----------------
// One wave per 16 rows; lane owns 8 contiguous columns. Tree-reduced fp32 dot
// (error ~1e-2 vs top-2 w-gaps of O(100) -> softmax is exactly one-hot either way).
// Emits per-wave partial (M, S, O[512]); no atomics, no zero-init.
__global__ __launch_bounds__(256) void online_pool(const float* __restrict__ x,
                                                   const float* __restrict__ P1,
                                                   float* __restrict__ Mp,
                                                   float* __restrict__ Sp,
                                                   float* __restrict__ Op) {
    const int b = blockIdx.x, c = blockIdx.y;
    const int wid = threadIdx.x >> 6, lane = threadIdx.x & 63;

    // s at lane's 8 columns = sum of C1 chunk partials (L2-resident, 2 MB total)
    float4 s0 = {0.f,0.f,0.f,0.f}, s1 = {0.f,0.f,0.f,0.f};
    const float4* pp = (const float4*)P1 + (size_t)b * C1 * (D / 4) + lane * 2;
    #pragma unroll
    for (int k = 0; k < C1; ++k) {
        float4 a = pp[k * (D / 4)], q = pp[k * (D / 4) + 1];
        s0.x += a.x; s0.y += a.y; s0.z += a.z; s0.w += a.w;
        s1.x += q.x; s1.y += q.y; s1.z += q.z; s1.w += q.w;
    }

    float m = -INFINITY, ssum = 0.f;
    float4 O0 = {0.f,0.f,0.f,0.f}, O1 = {0.f,0.f,0.f,0.f};
    const int t0 = c * R2 + wid * (R2 / 4);
    const float4* xr = (const float4*)x + ((size_t)(b * T + t0) * D >> 2) + lane * 2;

    #pragma unroll 2
    for (int i = 0; i < R2 / 4; ++i) {
        float4 x0 = xr[0], x1 = xr[1];
        xr += D / 4;
        float a;
        a =      x0.x * (s0.x - x0.x);
        a = fmaf(x0.y,  s0.y - x0.y, a);
        a = fmaf(x0.z,  s0.z - x0.z, a);
        a = fmaf(x0.w,  s0.w - x0.w, a);
        a = fmaf(x1.x,  s1.x - x1.x, a);
        a = fmaf(x1.y,  s1.y - x1.y, a);
        a = fmaf(x1.z,  s1.z - x1.z, a);
        a = fmaf(x1.w,  s1.w - x1.w, a);
        #pragma unroll
        for (int off = 1; off < 64; off <<= 1)
            a += __shfl_xor(a, off, 64);
        const float wr = a;                       // identical on all lanes
        if (wr <= m) {                            // wave-uniform branch
            const float e = __expf(wr - m);
            ssum += e;
            O0.x = fmaf(e, x0.x, O0.x); O0.y = fmaf(e, x0.y, O0.y);
            O0.z = fmaf(e, x0.z, O0.z); O0.w = fmaf(e, x0.w, O0.w);
            O1.x = fmaf(e, x1.x, O1.x); O1.y = fmaf(e, x1.y, O1.y);
            O1.z = fmaf(e, x1.z, O1.z); O1.w = fmaf(e, x1.w, O1.w);
        } else {
            const float al = __expf(m - wr);      // exp(-inf)=0 handles first iter
            ssum = fmaf(ssum, al, 1.f);
            O0.x = fmaf(O0.x, al, x0.x); O0.y = fmaf(O0.y, al, x0.y);
            O0.z = fmaf(O0.z, al, x0.z); O0.w = fmaf(O0.w, al, x0.w);
            O1.x = fmaf(O1.x, al, x1.x); O1.y = fmaf(O1.y, al, x1.y);
            O1.z = fmaf(O1.z, al, x1.z); O1.w = fmaf(O1.w, al, x1.w);
            m = wr;
        }
    }

    const int pi = (b * C2 + c) * 4 + wid;        // partial index: b*128 + ...
    if (lane == 0) { Mp[pi] = m; Sp[pi] = ssum; }
    float4* op = (float4*)Op + (size_t)pi * (D / 4) + lane * 2;
    op[0] = O0; op[1] = O1;
}

// ---------------- K3: merge 128 partials per batch ----------------
__global__ __launch_bounds__(128) void finalize(const float* __restrict__ Mp,
                                                const float* __restrict__ Sp,
                                                const float* __restrict__ Op,
                                                float* __restrict__ out) {
    const int b = blockIdx.x, tid = threadIdx.x;  // 128 threads = 2 waves
    const int wid = tid >> 6;
    __shared__ float fsh[NPART];
    __shared__ float red[2];

    const float Mc = Mp[b * NPART + tid];
    float m = Mc;
    #pragma unroll
    for (int off = 1; off < 64; off <<= 1) m = fmaxf(m, __shfl_xor(m, off, 64));
    if ((tid & 63) == 0) red[wid] = m;
    __syncthreads();
    const float Mg = fmaxf(red[0], red[1]);
    __syncthreads();

    const float f = __expf(Mc - Mg);
    fsh[tid] = f;
    float sp = Sp[b * NPART + tid] * f;
    #pragma unroll
    for (int off = 1; off < 64; off <<= 1) sp += __shfl_xor(sp, off, 64);
    if ((tid & 63) == 0) red[wid] = sp;
    __syncthreads();
    const float Sg = red[0] + red[1];

    float4 acc = {0.f,0.f,0.f,0.f};
    const float4* op = (const float4*)Op + (size_t)b * NPART * (D / 4) + tid;
    #pragma unroll 4
    for (int c = 0; c < NPART; ++c) {
        const float fc = fsh[c];
        float4 v = op[(size_t)c * (D / 4)];
        acc.x = fmaf(fc, v.x, acc.x); acc.y = fmaf(fc, v.y, acc.y);
        acc.z = fmaf(fc, v.z, acc.z); acc.w = fmaf(fc, v.w, acc.w);
    }
    const float inv = 1.0f / Sg;
    acc.x *= inv; acc.y *= inv; acc.z *= inv; acc.w *= inv;
    ((float4*)out)[(size_t)b * (D / 4) + tid] = acc;
}

extern "C" void kernel_launch(void* const* d_in, const int* in_sizes, int n_in,
                              void* d_out, int out_size, void* d_ws, size_t ws_size,
                              hipStream_t stream) {
    const float* x = (const float*)d_in[0];
    float* out = (float*)d_out;

    float* P1 = (float*)d_ws;                 // B*C1*D  = 2 MB
    float* Mp = P1 + (size_t)B * C1 * D;      // B*NPART = 16 KB
    float* Sp = Mp + (size_t)B * NPART;       // B*NPART = 16 KB
    float* Op = Sp + (size_t)B * NPART;       // B*NPART*D = 8 MB

    colsum_part<<<dim3(B, C1), 256, 0, stream>>>(x, P1);
    online_pool<<<dim3(B, C2), 256, 0, stream>>>(x, P1, Mp, Sp, Op);
    finalize<<<B, 128, 0, stream>>>(Mp, Sp, Op, out);
}

// Round 5
// 225.137 us; speedup vs baseline: 1.0428x; 1.0428x over previous
//
#include <hip/hip_runtime.h>
#include <math.h>

// (B,T,D) = (32, 2048, 512), fp32 in, fp32 out.
constexpr int B = 32;
constexpr int T = 2048;
constexpr int D = 512;

constexpr int C1 = 32;            // K1: chunks over T (1024 blocks)
constexpr int R1 = T / C1;        // 64 rows per K1 block
constexpr int C2 = 64;            // K2: blocks per batch
constexpr int RW = 8;             // rows per wave in K2
constexpr int NPART = C2 * 4;     // 256 wave-partials per batch

// ---------------- K1: partial column sums ----------------
// P1[b][c][d] = sum_{t in chunk c} x[b][t][d]
__global__ __launch_bounds__(256) void colsum_part(const float* __restrict__ x,
                                                   float* __restrict__ P1) {
    const int b = blockIdx.x, c = blockIdx.y;
    const int d4 = threadIdx.x & 127;      // float4 column
    const int rp = threadIdx.x >> 7;       // row parity
    const float4* xp = (const float4*)x + ((size_t)(b * T + c * R1) * D >> 2)
                       + (size_t)rp * (D / 4) + d4;
    float4 acc = {0.f, 0.f, 0.f, 0.f};
    #pragma unroll 8
    for (int i = 0; i < R1 / 2; ++i) {
        float4 v = xp[(size_t)i * (D / 2)];
        acc.x += v.x; acc.y += v.y; acc.z += v.z; acc.w += v.w;
    }
    __shared__ float4 lds[128];
    if (rp == 1) lds[d4] = acc;
    __syncthreads();
    if (rp == 0) {
        float4 o = lds[d4];
        acc.x += o.x; acc.y += o.y; acc.z += o.z; acc.w += o.w;
        ((float4*)P1)[(size_t)(b * C1 + c) * (D / 4) + d4] = acc;
    }
}

// ---------------- K1b: s[b] = sum_c P1[b][c]; zero out[b] ----------------
__global__ __launch_bounds__(256) void reduce_s(const float* __restrict__ P1,
                                                float* __restrict__ s,
                                                float* __restrict__ out) {
    const int b = blockIdx.x;
    const int d4 = threadIdx.x & 127, half = threadIdx.x >> 7;
    const float4* pp = (const float4*)P1 + ((size_t)b * C1 + half * (C1 / 2)) * (D / 4) + d4;
    float4 acc = {0.f, 0.f, 0.f, 0.f};
    #pragma unroll
    for (int k = 0; k < C1 / 2; ++k) {
        float4 v = pp[(size_t)k * (D / 4)];
        acc.x += v.x; acc.y += v.y; acc.z += v.z; acc.w += v.w;
    }
    __shared__ float4 lds[128];
    if (half == 1) {
        lds[d4] = acc;
        ((float4*)out)[(size_t)b * (D / 4) + d4] = make_float4(0.f, 0.f, 0.f, 0.f);
    }
    __syncthreads();
    if (half == 0) {
        float4 o = lds[d4];
        acc.x += o.x; acc.y += o.y; acc.z += o.z; acc.w += o.w;
        ((float4*)s)[(size_t)b * (D / 4) + d4] = acc;
    }
}

// ---------------- K2: fused rowdot + softmax-partial + pool ----------------
// One wave per 8 rows; x held in registers. Phase A: 8 independent dots (no
// cross-lane). Phase B: ONE pipelined xor-butterfly over 8 values (chain depth
// 6 total, ILP 8). Phase C: max/exp/weight from registers. No per-row serial
// shuffle chain (R4's bottleneck), no online-softmax branch.
__global__ __launch_bounds__(256) void fused_pool(const float* __restrict__ x,
                                                  const float* __restrict__ s,
                                                  float* __restrict__ Mp,
                                                  float* __restrict__ Sp,
                                                  float* __restrict__ Op) {
    const int b = blockIdx.x, c = blockIdx.y;
    const int wid = threadIdx.x >> 6, lane = threadIdx.x & 63;

    const float4* sp4 = (const float4*)(s + (size_t)b * D) + lane * 2;
    const float4 s0 = sp4[0], s1 = sp4[1];

    const int t0 = c * (RW * 4) + wid * RW;
    const float4* xr = (const float4*)(x + ((size_t)b * T + t0) * D) + lane * 2;

    // Phase A: load 8 rows (16 independent 16B loads) + 8 independent dots
    float4 X0[RW], X1[RW];
    #pragma unroll
    for (int r = 0; r < RW; ++r) {
        X0[r] = xr[0]; X1[r] = xr[1];
        xr += D / 4;
    }
    float a[RW];
    #pragma unroll
    for (int r = 0; r < RW; ++r) {
        float t;
        t =      X0[r].x * (s0.x - X0[r].x);
        t = fmaf(X0[r].y,  s0.y - X0[r].y, t);
        t = fmaf(X0[r].z,  s0.z - X0[r].z, t);
        t = fmaf(X0[r].w,  s0.w - X0[r].w, t);
        t = fmaf(X1[r].x,  s1.x - X1[r].x, t);
        t = fmaf(X1[r].y,  s1.y - X1[r].y, t);
        t = fmaf(X1[r].z,  s1.z - X1[r].z, t);
        t = fmaf(X1[r].w,  s1.w - X1[r].w, t);
        a[r] = t;
    }

    // Phase B: pipelined butterfly — 6 steps, 8 independent permutes per step
    #pragma unroll
    for (int off = 1; off < 64; off <<= 1) {
        #pragma unroll
        for (int r = 0; r < RW; ++r)
            a[r] += __shfl_xor(a[r], off, 64);
    }

    // Phase C: softmax partial over the 8 rows, weight register-held x
    float m = fmaxf(fmaxf(fmaxf(a[0], a[1]), fmaxf(a[2], a[3])),
                    fmaxf(fmaxf(a[4], a[5]), fmaxf(a[6], a[7])));
    float e[RW], ssum = 0.f;
    #pragma unroll
    for (int r = 0; r < RW; ++r) { e[r] = __expf(a[r] - m); ssum += e[r]; }

    float4 O0 = {0.f,0.f,0.f,0.f}, O1 = {0.f,0.f,0.f,0.f};
    #pragma unroll
    for (int r = 0; r < RW; ++r) {
        O0.x = fmaf(e[r], X0[r].x, O0.x); O0.y = fmaf(e[r], X0[r].y, O0.y);
        O0.z = fmaf(e[r], X0[r].z, O0.z); O0.w = fmaf(e[r], X0[r].w, O0.w);
        O1.x = fmaf(e[r], X1[r].x, O1.x); O1.y = fmaf(e[r], X1[r].y, O1.y);
        O1.z = fmaf(e[r], X1[r].z, O1.z); O1.w = fmaf(e[r], X1[r].w, O1.w);
    }

    const int pi = (b * C2 + c) * 4 + wid;        // 256 partials per batch
    if (lane == 0) { Mp[pi] = m; Sp[pi] = ssum; }
    float4* op = (float4*)Op + (size_t)pi * (D / 4) + lane * 2;
    op[0] = O0; op[1] = O1;
}

// ---------------- K3: merge 256 partials per batch, grid (B,8) ----------------
__global__ __launch_bounds__(256) void merge_out(const float* __restrict__ Mp,
                                                 const float* __restrict__ Sp,
                                                 const float* __restrict__ Op,
                                                 float* __restrict__ out) {
    const int b = blockIdx.x, j = blockIdx.y;
    const int tid = threadIdx.x, wid = tid >> 6, lane = tid & 63;
    __shared__ float fsh[NPART];
    __shared__ float red[4];

    // global M over the batch's 256 partials (one per thread)
    const float Mc = Mp[b * NPART + tid];
    float m = Mc;
    #pragma unroll
    for (int off = 1; off < 64; off <<= 1) m = fmaxf(m, __shfl_xor(m, off, 64));
    if (lane == 0) red[wid] = m;
    __syncthreads();
    const float Mg = fmaxf(fmaxf(red[0], red[1]), fmaxf(red[2], red[3]));
    __syncthreads();

    const float f = __expf(Mc - Mg);
    fsh[tid] = f;
    float spv = Sp[b * NPART + tid] * f;
    #pragma unroll
    for (int off = 1; off < 64; off <<= 1) spv += __shfl_xor(spv, off, 64);
    if (lane == 0) red[wid] = spv;
    __syncthreads();
    const float Sg = red[0] + red[1] + red[2] + red[3];
    const float inv = 1.0f / Sg;

    // this block accumulates its 32 partials (2 half-ranges of 16)
    const int d4 = tid & 127, pr = tid >> 7;
    const int p0 = j * 32 + pr * 16;
    float4 acc = {0.f,0.f,0.f,0.f};
    const float4* op = (const float4*)Op + ((size_t)b * NPART + p0) * (D / 4) + d4;
    #pragma unroll 4
    for (int i = 0; i < 16; ++i) {
        const float fc = fsh[p0 + i];
        float4 v = op[(size_t)i * (D / 4)];
        acc.x = fmaf(fc, v.x, acc.x); acc.y = fmaf(fc, v.y, acc.y);
        acc.z = fmaf(fc, v.z, acc.z); acc.w = fmaf(fc, v.w, acc.w);
    }
    float* o = out + (size_t)b * D + d4 * 4;
    atomicAdd(o + 0, acc.x * inv);
    atomicAdd(o + 1, acc.y * inv);
    atomicAdd(o + 2, acc.z * inv);
    atomicAdd(o + 3, acc.w * inv);
}

extern "C" void kernel_launch(void* const* d_in, const int* in_sizes, int n_in,
                              void* d_out, int out_size, void* d_ws, size_t ws_size,
                              hipStream_t stream) {
    const float* x = (const float*)d_in[0];
    float* out = (float*)d_out;

    float* P1 = (float*)d_ws;                  // B*C1*D   = 2 MB
    float* s  = P1 + (size_t)B * C1 * D;       // B*D      = 64 KB
    float* Mp = s + (size_t)B * D;             // B*NPART  = 32 KB
    float* Sp = Mp + (size_t)B * NPART;        // B*NPART  = 32 KB
    float* Op = Sp + (size_t)B * NPART;        // B*NPART*D = 16 MB

    colsum_part<<<dim3(B, C1), 256, 0, stream>>>(x, P1);
    reduce_s<<<B, 256, 0, stream>>>(P1, s, out);
    fused_pool<<<dim3(B, C2), 256, 0, stream>>>(x, s, Mp, Sp, Op);
    merge_out<<<dim3(B, 8), 256, 0, stream>>>(Mp, Sp, Op, out);
}